// Round 5
// baseline (383.669 us; speedup 1.0000x reference)
//
#include <hip/hip_runtime.h>
#include <cstdint>
#include <cstddef>

// ================= VQ layer: N=32768 pts, D=256, K=8192 codes ==================
// prepE (LDS-transpose, 512 blocks) -> e2z (from Et, 2048 blocks, + zero) ->
// screen (f16 MFMA, NO LDS: B streamed global->register dwordx4, dbuf named
// reg arrays, compiler-counted vmcnt, zero barriers; qtr=blockIdx&3 pins one
// 1MB EhP quarter per XCD L2) -> merge -> rescan (dbuf LDS) -> exact -> gather
#define NPTS    32768
#define DDIM    256
#define KCOD    8192
#define NELEM   8388608           // NPTS*DDIM
#define BIAS    4096.0f
#define WINDOW  8.0f              // ~11 sigma of f16-score error model
#define FLAGCAP 16384
#define CANDCAP 16

typedef _Float16 half8 __attribute__((ext_vector_type(8)));
typedef float    f32x4 __attribute__((ext_vector_type(4)));

__device__ __forceinline__ unsigned umin_(unsigned a, unsigned b){ return a<b?a:b; }
__device__ __forceinline__ unsigned umax_(unsigned a, unsigned b){ return a>b?a:b; }

// async global->LDS, 16B per lane (still used by rescan)
__device__ __forceinline__ void gl_lds16(const void* g, void* l) {
  __builtin_amdgcn_global_load_lds(
      (const __attribute__((address_space(1))) unsigned int*)g,
      (__attribute__((address_space(3))) unsigned int*)l, 16, 0, 0);
}

// --------------------------------------------------------------- prepE
// 512 blocks = 128 colgroups x 4 dsteps; per block: 64 cols x 64 d tile.
// EhP elem idx = chunk*8192 + (st*2+nb)*512 + (q*16+n16)*8 + j
//   where col = chunk*32 + nb*16 + n16, d = st*32 + q*8 + j.
__global__ void k_prepE(const float* __restrict__ E, _Float16* __restrict__ EhP,
                        float* __restrict__ Et) {
  __shared__ float T[64][65];
  const int tid = threadIdx.x;
  const int cg = blockIdx.x & 127, dstep = blockIdx.x >> 7;
  const int k0 = cg*64, c0 = cg*2;
  { // load 64 d x 64 k, coalesced within 256B rows
    const int kl = tid & 63, wq = tid >> 6;
    #pragma unroll
    for (int rr = 0; rr < 16; ++rr) {
      int dl = rr*4 + wq;
      T[dl][kl] = E[(size_t)(dstep*64 + dl)*KCOD + k0 + kl];
    }
  }
  __syncthreads();
  { // Et rows: [k][d] contiguous
    const int kk = tid >> 2, fq = tid & 3;
    #pragma unroll
    for (int iter = 0; iter < 4; ++iter) {
      int db = iter*16 + fq*4;
      float4 v = make_float4(T[db][kk], T[db+1][kk], T[db+2][kk], T[db+3][kk]);
      *(float4*)(Et + (size_t)(k0+kk)*DDIM + dstep*64 + db) = v;
    }
  }
  { // EhP frag-order (512 groups of 8 this dstep)
    #pragma unroll
    for (int gi = 0; gi < 2; ++gi) {
      int g = gi*256 + tid;
      int n16 = g & 15, q = (g>>4)&3, nb = (g>>6)&1, stp = (g>>7)&1, ch = (g>>8)&1;
      int st = dstep*2 + stp;
      int kl2 = ch*32 + nb*16 + n16;
      int dl = stp*32 + q*8;
      half8 h;
      #pragma unroll
      for (int j = 0; j < 8; ++j) h[j] = (_Float16)(16.0f * T[dl + j][kl2]);
      *(half8*)(EhP + (size_t)(c0+ch)*8192 + (st*2+nb)*512 + (q*16+n16)*8) = h;
    }
  }
}

// --- e2n[k] = -0.5*(256*||E_k||^2 + BIAS)  (acc-domain init value) + zeroing
__global__ void k_e2z(const float* __restrict__ Et, float* __restrict__ e2n,
                      int* __restrict__ ccounts, int* __restrict__ flagcount,
                      float* __restrict__ out_loss) {
  const int lane = threadIdx.x & 63, wid = threadIdx.x >> 6;
  const int k = blockIdx.x*4 + wid;                     // 2048 blocks
  float4 v = *((const float4*)(Et + (size_t)k*DDIM) + lane);
  float s = v.x*v.x + v.y*v.y + v.z*v.z + v.w*v.w;
  #pragma unroll
  for (int off = 1; off < 64; off <<= 1) s += __shfl_xor(s, off);
  if (lane == 0) e2n[k] = fmaf(-128.0f, s, -0.5f*BIAS);
  int t = blockIdx.x*256 + threadIdx.x;
  if (t < FLAGCAP) ccounts[t] = 0;
  if (t == 0) { *flagcount = 0; *out_loss = 0.0f; }
}

// --------------------------------------------------------- P1: f16 MFMA screen
// 512 blocks; qtr = blockIdx&3 (round-robin XCD dispatch -> each XCD streams
// ONE 1MB EhP quarter, L2-resident); rowgroup = blockIdx>>2 (256 rows/block,
// 64 rows/wave). Each wave scans its 2048-col quarter in 128 private 16-col
// chunks; B fragments are contiguous 16B/lane global loads (dwordx4) into
// double-buffered NAMED register arrays -> no LDS, no barriers; compiler
// inserts counted vmcnt per use. acc starts at e2n[col] so acc_final = -s/2;
// packed (bits & 0xFFFFE000)|col tracked with umin/umed3.
// NB quarter stride = 64 chunks * 8192 halfs * 2B = 1048576 bytes (R3 bug: 2MB).
__launch_bounds__(256, 2)
__global__ void k_screen(const float* __restrict__ X, const _Float16* __restrict__ EhP,
                         const float* __restrict__ e2n, unsigned* __restrict__ m1q,
                         unsigned* __restrict__ m2q)
{
  const int tid = threadIdx.x;
  const int lane = tid & 63, wid = tid >> 6;
  const int q = lane >> 4, lp = lane & 15;
  const int qtr = blockIdx.x & 3, rg = blockIdx.x >> 2;
  const int rowbase = rg*256 + wid*64;

  // quarter base for B stream; chunk c (0..127): 16 cols, frag (st,lane) at
  // byte (c>>1)*16384 + (c&1)*1024 + st*2048 + lane*16  (16B contiguous/lane)
  const char* gq = (const char*)EhP + (size_t)qtr*1048576 + lane*16;
  const float* ezq = e2n + qtr*2048 + lp;

  // A fragments: 64 rows/wave, register(AGPR)-resident
  half8 af[4][8];
  #pragma unroll
  for (int mb = 0; mb < 4; ++mb) {
    const float* xr = X + (size_t)(rowbase + mb*16 + lp)*DDIM;
    #pragma unroll
    for (int st = 0; st < 8; ++st) {
      const float* p = xr + st*32 + q*8;
      float4 v0 = *(const float4*)p;
      float4 v1 = *(const float4*)(p + 4);
      half8 h;
      h[0]=(_Float16)(16.f*v0.x); h[1]=(_Float16)(16.f*v0.y);
      h[2]=(_Float16)(16.f*v0.z); h[3]=(_Float16)(16.f*v0.w);
      h[4]=(_Float16)(16.f*v1.x); h[5]=(_Float16)(16.f*v1.y);
      h[6]=(_Float16)(16.f*v1.z); h[7]=(_Float16)(16.f*v1.w);
      af[mb][st] = h;
    }
  }

  unsigned m1u[4][4], m2u[4][4];
  #pragma unroll
  for (int mb=0;mb<4;++mb)
    #pragma unroll
    for (int r=0;r<4;++r) { m1u[mb][r]=0xFFFFFFFFu; m2u[mb][r]=0xFFFFFFFFu; }

  half8 bfA[8], bfB[8];
  float ezA, ezB;

  #define LOADB(c, bf, ez) do {                                              \
    const char* g_ = gq + (size_t)((c)>>1)*16384 + (size_t)((c)&1)*1024;     \
    _Pragma("unroll")                                                        \
    for (int st_ = 0; st_ < 8; ++st_)                                        \
      bf[st_] = *(const half8*)(g_ + st_*2048);                              \
    ez = ezq[(c)*16];                                                        \
  } while (0)

  #define COMPUTEC(c, bf, ez) do {                                           \
    f32x4 acc_[4];                                                           \
    _Pragma("unroll")                                                        \
    for (int mb_=0;mb_<4;++mb_) { f32x4 a_={ez,ez,ez,ez}; acc_[mb_]=a_; }    \
    __builtin_amdgcn_s_setprio(1);                                           \
    _Pragma("unroll")                                                        \
    for (int st_ = 0; st_ < 8; ++st_) {                                      \
      _Pragma("unroll")                                                      \
      for (int mb_ = 0; mb_ < 4; ++mb_)                                      \
        acc_[mb_] = __builtin_amdgcn_mfma_f32_16x16x32_f16(af[mb_][st_],     \
                        bf[st_], acc_[mb_], 0, 0, 0);                        \
    }                                                                        \
    __builtin_amdgcn_s_setprio(0);                                           \
    const unsigned colu_ = (unsigned)(qtr*2048 + (c)*16 + lp);               \
    _Pragma("unroll")                                                        \
    for (int mb_ = 0; mb_ < 4; ++mb_)                                        \
      _Pragma("unroll")                                                      \
      for (int r_ = 0; r_ < 4; ++r_) {                                       \
        unsigned us_ = (__float_as_uint(acc_[mb_][r_]) & 0xFFFFE000u) | colu_;\
        unsigned o1_ = m1u[mb_][r_];                                         \
        m2u[mb_][r_] = umin_(m2u[mb_][r_], umax_(o1_, us_));                 \
        m1u[mb_][r_] = umin_(o1_, us_);                                      \
      }                                                                      \
  } while (0)

  LOADB(0, bfA, ezA);
  LOADB(1, bfB, ezB);
  #pragma unroll 1
  for (int c = 0; c < 126; c += 2) {
    COMPUTEC(c, bfA, ezA);
    LOADB(c + 2, bfA, ezA);
    COMPUTEC(c + 1, bfB, ezB);
    LOADB(c + 3, bfB, ezB);
  }
  COMPUTEC(126, bfA, ezA);
  COMPUTEC(127, bfB, ezB);
  #undef LOADB
  #undef COMPUTEC

  // merge across the 16 lp-lanes of each quad (waves own disjoint rows)
  #pragma unroll
  for (int off = 1; off <= 8; off <<= 1) {
    #pragma unroll
    for (int mb=0;mb<4;++mb)
      #pragma unroll
      for (int r=0;r<4;++r) {
        unsigned o1 = (unsigned)__shfl_xor((int)m1u[mb][r], off);
        unsigned o2 = (unsigned)__shfl_xor((int)m2u[mb][r], off);
        unsigned hi = umax_(m1u[mb][r], o1);
        m2u[mb][r] = umin_(umin_(m2u[mb][r], o2), hi);
        m1u[mb][r] = umin_(m1u[mb][r], o1);
      }
  }
  if (lp == 0) {
    #pragma unroll
    for (int mb=0;mb<4;++mb)
      #pragma unroll
      for (int r=0;r<4;++r) {
        int row = rowbase + mb*16 + q*4 + r;
        m1q[qtr*NPTS + row] = m1u[mb][r];
        m2q[qtr*NPTS + row] = m2u[mb][r];
      }
  }
}

// ------------------------------------- merge 4 quarters, write idx/m1s, flag
// All values are packed acc-domain (negative floats): umin == min score.
// s2-s1 < W  <=>  a1-a2 < W/2.
__global__ void k_merge(const unsigned* __restrict__ m1q, const unsigned* __restrict__ m2q,
                        int* __restrict__ idx, float* __restrict__ m1s,
                        int* __restrict__ flaglist, int* __restrict__ flagcount)
{
  const int row = blockIdx.x*256 + threadIdx.x;   // 128 blocks
  unsigned u0 = m1q[row], u1 = m1q[NPTS + row], u2 = m1q[2*NPTS + row], u3 = m1q[3*NPTS + row];
  unsigned w0 = m2q[row], w1 = m2q[NPTS + row], w2 = m2q[2*NPTS + row], w3 = m2q[3*NPTS + row];
  unsigned a = umin_(u0,u1), b = umax_(u0,u1), cx = umin_(u2,u3), d = umax_(u2,u3);
  unsigned m1g = umin_(a, cx);
  unsigned sec = umin_(umax_(a, cx), umin_(b, d));
  unsigned m2g = umin_(umin_(umin_(w0,w1), umin_(w2,w3)), sec);
  float m1f = __uint_as_float(m1g & 0xFFFFE000u);   // = -s1/2
  float m2f = __uint_as_float(m2g & 0xFFFFE000u);   // = -s2/2
  idx[row] = (int)(m1g & 0x1FFFu);
  m1s[row] = m1f;
  if (m1f - m2f < 0.5f*WINDOW) {
    int p = atomicAdd(flagcount, 1);
    if (p < FLAGCAP) flaglist[p] = row;
  }
}

// -------------------------------- P2: rescan flagged rows, collect candidates
// grid 512 = 16 batch-slots x 32 K-slices (8 chunks each), dbuf LDS staging.
// acc-domain: candidate iff acc > m1s - W/2  (<=> s < s1 + W).
__launch_bounds__(256, 2)
__global__ void k_rescan(const float* __restrict__ X, const _Float16* __restrict__ EhP,
                         const float* __restrict__ e2n, const float* __restrict__ m1s,
                         const int* __restrict__ flaglist, const int* __restrict__ flagcount,
                         int* __restrict__ ccounts, int* __restrict__ candbuf)
{
  __shared__ __align__(16) _Float16 Bsh[2][8192];
  const int tid = threadIdx.x, lane = tid & 63, wid = tid >> 6;
  const int q = lane >> 4, lp = lane & 15;
  const int slice = blockIdx.x & 31, bslot = blockIdx.x >> 5;
  const int stag = wid*1024 + lane*16;
  int cnt = *flagcount; if (cnt > FLAGCAP) cnt = FLAGCAP;

  for (int batch = bslot; batch*256 < cnt; batch += 16) {
    const int base = batch*256 + wid*64;
    { // issue chunk slice*8 staging (overlaps A build)
      const char* g = (const char*)(EhP + (size_t)(slice*8)*8192);
      #pragma unroll
      for (int r = 0; r < 4; ++r)
        gl_lds16(g + r*4096 + stag, (char*)&Bsh[0][0] + r*4096 + stag);
    }
    int ga[4];
    #pragma unroll
    for (int mb=0;mb<4;++mb) {
      int fi = base + mb*16 + lp;
      ga[mb] = (fi < cnt) ? flaglist[fi] : 0;
    }
    float thr[4][4]; int fis[4][4];
    #pragma unroll
    for (int mb=0;mb<4;++mb)
      #pragma unroll
      for (int r=0;r<4;++r) {
        int fi = base + mb*16 + q*4 + r;
        fis[mb][r] = fi;
        if (fi < cnt) thr[mb][r] = m1s[flaglist[fi]] - 0.5f*WINDOW;
        else          thr[mb][r] = 3.0e38f;      // acc is negative: never true
      }
    half8 af[4][8];
    #pragma unroll
    for (int mb = 0; mb < 4; ++mb) {
      const float* xr = X + (size_t)ga[mb]*DDIM;
      #pragma unroll
      for (int st = 0; st < 8; ++st) {
        const float* p = xr + st*32 + q*8;
        float4 v0 = *(const float4*)p;
        float4 v1 = *(const float4*)(p + 4);
        half8 h;
        h[0]=(_Float16)(16.f*v0.x); h[1]=(_Float16)(16.f*v0.y);
        h[2]=(_Float16)(16.f*v0.z); h[3]=(_Float16)(16.f*v0.w);
        h[4]=(_Float16)(16.f*v1.x); h[5]=(_Float16)(16.f*v1.y);
        h[6]=(_Float16)(16.f*v1.z); h[7]=(_Float16)(16.f*v1.w);
        af[mb][st] = h;
      }
    }
    float ezn0 = e2n[slice*256 + lp];
    float ezn1 = e2n[slice*256 + 16 + lp];
    for (int j = 0; j < 8; ++j) {
      const int cur = j & 1;
      const float ez0 = ezn0, ez1 = ezn1;
      __syncthreads();
      if (j + 1 < 8) {
        const char* g = (const char*)(EhP + (size_t)(slice*8 + j + 1)*8192);
        #pragma unroll
        for (int r = 0; r < 4; ++r)
          gl_lds16(g + r*4096 + stag, (char*)&Bsh[cur^1][0] + r*4096 + stag);
        ezn0 = e2n[slice*256 + (j+1)*32 + lp];
        ezn1 = e2n[slice*256 + (j+1)*32 + 16 + lp];
      }
      f32x4 acc[4][2];
      #pragma unroll
      for (int mb=0;mb<4;++mb) {
        f32x4 a0 = {ez0, ez0, ez0, ez0};
        f32x4 a1 = {ez1, ez1, ez1, ez1};
        acc[mb][0] = a0; acc[mb][1] = a1;
      }
      #pragma unroll
      for (int st = 0; st < 8; ++st) {
        half8 bf[2];
        bf[0] = *(const half8*)(&Bsh[cur][(st*2+0)*512 + lane*8]);
        bf[1] = *(const half8*)(&Bsh[cur][(st*2+1)*512 + lane*8]);
        #pragma unroll
        for (int nb = 0; nb < 2; ++nb)
          #pragma unroll
          for (int mb = 0; mb < 4; ++mb)
            acc[mb][nb] = __builtin_amdgcn_mfma_f32_16x16x32_f16(af[mb][st], bf[nb], acc[mb][nb], 0, 0, 0);
      }
      const int c = slice*8 + j;
      #pragma unroll
      for (int nb = 0; nb < 2; ++nb) {
        const int col = c*32 + nb*16 + lp;
        #pragma unroll
        for (int mb = 0; mb < 4; ++mb)
          #pragma unroll
          for (int r = 0; r < 4; ++r) {
            if (acc[mb][nb][r] > thr[mb][r]) {
              int fi = fis[mb][r];
              int slot = atomicAdd(&ccounts[fi], 1);
              if (slot < CANDCAP) candbuf[fi*CANDCAP + slot] = col;
            }
          }
      }
    }
    __syncthreads();   // protect Bsh before next batch's preload
  }
}

// -------------------------------------- P3: exact fp64 argmin over candidates
__global__ void k_exact(const float* __restrict__ X, const float* __restrict__ Et,
                        const int* __restrict__ flaglist, const int* __restrict__ flagcount,
                        const int* __restrict__ ccounts, const int* __restrict__ candbuf,
                        int* __restrict__ idx)
{
  int cnt = *flagcount; if (cnt > FLAGCAP) cnt = FLAGCAP;
  const int lane = threadIdx.x & 63;
  const int w = blockIdx.x*4 + (threadIdx.x >> 6);      // 256 blocks -> 1024 waves
  for (int i = w; i < cnt; i += 1024) {
    const int g = flaglist[i];
    const int cc = ccounts[i];
    double best = 1.0e300; int bestk = 0x7FFFFFFF;
    if (cc <= CANDCAP) {
      float4 xv = *(const float4*)(X + (size_t)g*DDIM + lane*4);
      for (int c = 0; c < cc; ++c) {
        int k = candbuf[i*CANDCAP + c];
        float4 ev = *(const float4*)(Et + (size_t)k*DDIM + lane*4);
        double d0 = (double)xv.x - (double)ev.x, d1 = (double)xv.y - (double)ev.y;
        double d2 = (double)xv.z - (double)ev.z, d3 = (double)xv.w - (double)ev.w;
        double s = d0*d0 + d1*d1 + d2*d2 + d3*d3;
        #pragma unroll
        for (int off = 1; off < 64; off <<= 1) s += __shfl_xor(s, off);
        if (s < best || (s == best && k < bestk)) { best = s; bestk = k; }
      }
    } else {  // candbuf overflow: full exact scan (statistically ~never)
      double bb = 1.0e300; int bk = 0x7FFFFFFF;
      for (int k = lane; k < KCOD; k += 64) {
        double s = 0.0;
        for (int d = 0; d < DDIM; ++d) {
          double df = (double)X[(size_t)g*DDIM + d] - (double)Et[(size_t)k*DDIM + d];
          s += df*df;
        }
        if (s < bb || (s == bb && k < bk)) { bb = s; bk = k; }
      }
      #pragma unroll
      for (int off = 1; off < 64; off <<= 1) {
        double ob = __shfl_xor(bb, off); int ok = __shfl_xor(bk, off);
        if (ob < bb || (ob == bb && ok < bk)) { bb = ob; bk = ok; }
      }
      best = bb; bestk = bk;
    }
    if (lane == 0 && bestk != 0x7FFFFFFF) idx[g] = bestk;
  }
}

// -------------------------------------------------- P4: gather output + loss
__global__ void k_gather(const float* __restrict__ X, const float* __restrict__ Et,
                         const int* __restrict__ idx, float* __restrict__ out)
{
  const int lane = threadIdx.x & 63, wid = threadIdx.x >> 6;
  float lsum = 0.0f;
  for (int i = 0; i < 16; ++i) {
    int n = blockIdx.x*64 + i*4 + wid;
    int k = idx[n];
    float4 xv = *(const float4*)(X  + (size_t)n*DDIM + lane*4);
    float4 ev = *(const float4*)(Et + (size_t)k*DDIM + lane*4);
    *(float4*)(out + (size_t)n*DDIM + lane*4) = ev;   // ST fwd value == quantized
    float d0 = ev.x-xv.x, d1 = ev.y-xv.y, d2 = ev.z-xv.z, d3 = ev.w-xv.w;
    lsum += d0*d0 + d1*d1 + d2*d2 + d3*d3;
  }
  #pragma unroll
  for (int off = 1; off < 64; off <<= 1) lsum += __shfl_xor(lsum, off);
  if (lane == 0) atomicAdd(out + (size_t)NELEM, lsum * (1.25f/8388608.0f));
}

// ================================ launch ======================================
extern "C" void kernel_launch(void* const* d_in, const int* in_sizes, int n_in,
                              void* d_out, int out_size, void* d_ws, size_t ws_size,
                              hipStream_t stream)
{
  const float* X = (const float*)d_in[0];   // [32768][256]
  const float* E = (const float*)d_in[1];   // [256][8192]
  float* out = (float*)d_out;               // [8388608 quantized][1 loss]
  char* ws = (char*)d_ws;

  float*     Et        = (float*)(ws);                               // 8 MB
  _Float16*  EhP       = (_Float16*)(ws + 8388608);                  // 4 MB
  float*     e2n       = (float*)(ws + 12582912);                    // 32 KB
  unsigned*  m1q       = (unsigned*)(ws + 12615680);                 // 512 KB
  unsigned*  m2q       = (unsigned*)(ws + 13139968);                 // 512 KB
  float*     m1s       = (float*)(ws + 13664256);                    // 128 KB
  int*       idx       = (int*)(ws + 13795328);                      // 128 KB
  int*       flaglist  = (int*)(ws + 13926400);                      // 64 KB
  int*       ccounts   = (int*)(ws + 13991936);                      // 64 KB
  int*       candbuf   = (int*)(ws + 14057472);                      // 1 MB
  int*       flagcount = (int*)(ws + 15106048);                      // 4 B
  if (ws_size < (size_t)15106052) return;

  dim3 B(256);
  k_prepE <<<dim3(512),  B, 0, stream>>>(E, EhP, Et);
  k_e2z   <<<dim3(2048), B, 0, stream>>>(Et, e2n, ccounts, flagcount, out + NELEM);
  k_screen<<<dim3(512),  B, 0, stream>>>(X, EhP, e2n, m1q, m2q);
  k_merge <<<dim3(128),  B, 0, stream>>>(m1q, m2q, idx, m1s, flaglist, flagcount);
  k_rescan<<<dim3(512),  B, 0, stream>>>(X, EhP, e2n, m1s, flaglist, flagcount, ccounts, candbuf);
  k_exact <<<dim3(256),  B, 0, stream>>>(X, Et, flaglist, flagcount, ccounts, candbuf, idx);
  k_gather<<<dim3(512),  B, 0, stream>>>(X, Et, idx, out);
}

// Round 6
// 292.947 us; speedup vs baseline: 1.3097x; 1.3097x over previous
//
#include <hip/hip_runtime.h>
#include <cstdint>
#include <cstddef>

// ================= VQ layer: N=32768 pts, D=256, K=8192 codes ==================
// prepE (LDS-transpose, 512 blocks) -> e2z (from Et, 2048 blocks, + zero) ->
// screen (f16 MFMA, counted-vmcnt phase schedule: 4-buffer LDS ring, raw
// s_barrier WITHOUT vmcnt(0) drain, stage 2 chunks ahead, ds_read/MFMA/
// deferred-epilogue interleave per chunk) -> merge -> rescan (dbuf) ->
// exact (fp64) -> gather
#define NPTS    32768
#define DDIM    256
#define KCOD    8192
#define NELEM   8388608           // NPTS*DDIM
#define BIAS    4096.0f
#define WINDOW  8.0f              // ~11 sigma of f16-score error model
#define FLAGCAP 16384
#define CANDCAP 16

typedef _Float16 half8 __attribute__((ext_vector_type(8)));
typedef float    f32x4 __attribute__((ext_vector_type(4)));

__device__ __forceinline__ unsigned umin_(unsigned a, unsigned b){ return a<b?a:b; }
__device__ __forceinline__ unsigned umax_(unsigned a, unsigned b){ return a>b?a:b; }

// async global->LDS, 16B per lane; lds dest linear in lane order
__device__ __forceinline__ void gl_lds16(const void* g, void* l) {
  __builtin_amdgcn_global_load_lds(
      (const __attribute__((address_space(1))) unsigned int*)g,
      (__attribute__((address_space(3))) unsigned int*)l, 16, 0, 0);
}

// --------------------------------------------------------------- prepE
// 512 blocks = 128 colgroups x 4 dsteps; per block: 64 cols x 64 d tile.
// EhP elem idx = chunk32*8192 + (st*2+nb)*512 + (q*16+n16)*8 + j
//   where col = chunk32*32 + nb*16 + n16, d = st*32 + q*8 + j.
__global__ void k_prepE(const float* __restrict__ E, _Float16* __restrict__ EhP,
                        float* __restrict__ Et) {
  __shared__ float T[64][65];
  const int tid = threadIdx.x;
  const int cg = blockIdx.x & 127, dstep = blockIdx.x >> 7;
  const int k0 = cg*64, c0 = cg*2;
  { // load 64 d x 64 k, coalesced within 256B rows
    const int kl = tid & 63, wq = tid >> 6;
    #pragma unroll
    for (int rr = 0; rr < 16; ++rr) {
      int dl = rr*4 + wq;
      T[dl][kl] = E[(size_t)(dstep*64 + dl)*KCOD + k0 + kl];
    }
  }
  __syncthreads();
  { // Et rows: [k][d] contiguous
    const int kk = tid >> 2, fq = tid & 3;
    #pragma unroll
    for (int iter = 0; iter < 4; ++iter) {
      int db = iter*16 + fq*4;
      float4 v = make_float4(T[db][kk], T[db+1][kk], T[db+2][kk], T[db+3][kk]);
      *(float4*)(Et + (size_t)(k0+kk)*DDIM + dstep*64 + db) = v;
    }
  }
  { // EhP frag-order (512 groups of 8 this dstep)
    #pragma unroll
    for (int gi = 0; gi < 2; ++gi) {
      int g = gi*256 + tid;
      int n16 = g & 15, q = (g>>4)&3, nb = (g>>6)&1, stp = (g>>7)&1, ch = (g>>8)&1;
      int st = dstep*2 + stp;
      int kl2 = ch*32 + nb*16 + n16;
      int dl = stp*32 + q*8;
      half8 h;
      #pragma unroll
      for (int j = 0; j < 8; ++j) h[j] = (_Float16)(16.0f * T[dl + j][kl2]);
      *(half8*)(EhP + (size_t)(c0+ch)*8192 + (st*2+nb)*512 + (q*16+n16)*8) = h;
    }
  }
}

// --- e2n[k] = -0.5*(256*||E_k||^2 + BIAS)  (acc-domain init value) + zeroing
__global__ void k_e2z(const float* __restrict__ Et, float* __restrict__ e2n,
                      int* __restrict__ ccounts, int* __restrict__ flagcount,
                      float* __restrict__ out_loss) {
  const int lane = threadIdx.x & 63, wid = threadIdx.x >> 6;
  const int k = blockIdx.x*4 + wid;                     // 2048 blocks
  float4 v = *((const float4*)(Et + (size_t)k*DDIM) + lane);
  float s = v.x*v.x + v.y*v.y + v.z*v.z + v.w*v.w;
  #pragma unroll
  for (int off = 1; off < 64; off <<= 1) s += __shfl_xor(s, off);
  if (lane == 0) e2n[k] = fmaf(-128.0f, s, -0.5f*BIAS);
  int t = blockIdx.x*256 + threadIdx.x;
  if (t < FLAGCAP) ccounts[t] = 0;
  if (t == 0) { *flagcount = 0; *out_loss = 0.0f; }
}

// --------------------------------------------------------- P1: f16 MFMA screen
// 512 blocks = 4 col-quarters (blockIdx&3) x 128 rowgroups. 4 waves x 64 rows.
// Quarter scanned in 128 chunks of 16 cols. 4-buffer LDS ring, stage depth 2,
// per-chunk: vmcnt(2) [own stage landed, next in flight -- NEVER drains to 0
// until tail] -> s_barrier -> issue stage(cc+2) -> 8x{ds_read_b128, 4 MFMA,
// 2 deferred epilogue updates of chunk cc-1}. e2n staged to LDS so the loop's
// vmem stream is exactly 2 ops/chunk (vmcnt count stays exact). acc starts at
// e2n[col] so acc_final = -s/2 (negative); packed (bits&0xFFFFE000)|col via
// umin/umed3. Deferred epi uses accA/accB ping-pong (static idx); accB
// pre-init -inf => first epi is a packed-unsigned-huge no-op.
__launch_bounds__(256, 2)
__global__ void k_screen(const float* __restrict__ X, const _Float16* __restrict__ EhP,
                         const float* __restrict__ e2n, unsigned* __restrict__ m1q,
                         unsigned* __restrict__ m2q)
{
  __shared__ __align__(16) _Float16 Bsh[4][4096];   // 4 x 8 KB ring
  __shared__ __align__(16) float    E2s[2048];      // 8 KB e2n quarter
  const int tid = threadIdx.x;
  const int lane = tid & 63, wid = tid >> 6;
  const int q = lane >> 4, lp = lane & 15;
  const int qtr = blockIdx.x & 3, rg = blockIdx.x >> 2;
  const int rowbase = rg*256 + wid*64;
  const int lb = lane*16;
  const char* gq = (const char*)EhP + (size_t)qtr*1048576;   // 1 MB quarter

  // A fragments FIRST (64 vmem loads -> oldest in vm queue; the loop's first
  // vmcnt(2) guarantees they have landed without an explicit drain)
  half8 af[4][8];
  #pragma unroll
  for (int mb = 0; mb < 4; ++mb) {
    const float* xr = X + (size_t)(rowbase + mb*16 + lp)*DDIM;
    #pragma unroll
    for (int st = 0; st < 8; ++st) {
      const float* p = xr + st*32 + q*8;
      float4 v0 = *(const float4*)p;
      float4 v1 = *(const float4*)(p + 4);
      half8 h;
      h[0]=(_Float16)(16.f*v0.x); h[1]=(_Float16)(16.f*v0.y);
      h[2]=(_Float16)(16.f*v0.z); h[3]=(_Float16)(16.f*v0.w);
      h[4]=(_Float16)(16.f*v1.x); h[5]=(_Float16)(16.f*v1.y);
      h[6]=(_Float16)(16.f*v1.z); h[7]=(_Float16)(16.f*v1.w);
      af[mb][st] = h;
    }
  }

  // chunk cc staging: 8 KB = 8 slabs of 1 KB; wave wid stages slabs 2wid,2wid+1
  #define STAGE(cc, B) do {                                                   \
    const char* gs_ = gq + (size_t)((cc)>>1)*16384 + (size_t)((cc)&1)*1024    \
                         + wid*4096;                                          \
    char* ds_ = (char*)&Bsh[B][0] + wid*2048;                                 \
    gl_lds16(gs_ + lb, ds_ + lb);                                             \
    gl_lds16(gs_ + 2048 + lb, ds_ + 1024 + lb);                               \
  } while (0)

  { // stage e2n quarter (wave wid: slabs 2wid, 2wid+1), then chunks 0,1
    const char* ge = (const char*)(e2n + (size_t)qtr*2048) + wid*2048;
    gl_lds16(ge + lb, (char*)E2s + wid*2048 + lb);
    gl_lds16(ge + 1024 + lb, (char*)E2s + wid*2048 + 1024 + lb);
    STAGE(0, 0);
    STAGE(1, 1);
  }

  unsigned m1u[4][4], m2u[4][4];
  #pragma unroll
  for (int mb=0;mb<4;++mb)
    #pragma unroll
    for (int r=0;r<4;++r) { m1u[mb][r]=0xFFFFFFFFu; m2u[mb][r]=0xFFFFFFFFu; }

  f32x4 accA[4], accB[4];
  const float NEGINF = __uint_as_float(0xFF800000u);
  #pragma unroll
  for (int mb=0;mb<4;++mb) { f32x4 z = {NEGINF,NEGINF,NEGINF,NEGINF}; accB[mb] = z; }

  // one phase: wait own stage(cc), barrier, prefetch cc+2, compute cc into ACC
  // while folding chunk cc-1's epilogue (PACC) into the st-loop.
  #define SUBSTEP(cc, BUF, ACC, PACC, STCC, SBUF, WAITN, DO_STAGE) do {       \
    asm volatile("s_waitcnt vmcnt(" #WAITN ")" ::: "memory");                 \
    __builtin_amdgcn_s_barrier();                                             \
    __builtin_amdgcn_sched_barrier(0);                                        \
    if (DO_STAGE) { STAGE(STCC, SBUF); }                                      \
    const float ez_ = E2s[(cc)*16 + lp];                                      \
    _Pragma("unroll")                                                         \
    for (int mb_=0;mb_<4;++mb_){ f32x4 a_={ez_,ez_,ez_,ez_}; ACC[mb_]=a_; }   \
    const unsigned pcolu_ = (unsigned)(qtr*2048 + ((cc)-1)*16 + lp);          \
    __builtin_amdgcn_s_setprio(1);                                            \
    _Pragma("unroll")                                                         \
    for (int st_=0; st_<8; ++st_) {                                           \
      half8 bf_ = *(const half8*)((const char*)&Bsh[BUF][0] + st_*1024 + lb); \
      _Pragma("unroll")                                                       \
      for (int mb_=0;mb_<4;++mb_)                                             \
        ACC[mb_] = __builtin_amdgcn_mfma_f32_16x16x32_f16(af[mb_][st_], bf_,  \
                                                          ACC[mb_], 0, 0, 0); \
      _Pragma("unroll")                                                       \
      for (int k_=0;k_<2;++k_) {                                              \
        const int s_ = st_*2 + k_, mbp_ = s_>>2, rp_ = s_&3;                  \
        unsigned us_ = (__float_as_uint(PACC[mbp_][rp_]) & 0xFFFFE000u) | pcolu_; \
        unsigned o1_ = m1u[mbp_][rp_];                                        \
        m2u[mbp_][rp_] = umin_(m2u[mbp_][rp_], umax_(o1_, us_));              \
        m1u[mbp_][rp_] = umin_(o1_, us_);                                     \
      }                                                                       \
    }                                                                         \
    __builtin_amdgcn_s_setprio(0);                                            \
  } while (0)

  #pragma unroll 1
  for (int k = 0; k < 31; ++k) {
    const int cc = k*4;
    SUBSTEP(cc+0, 0, accA, accB, cc+2, 2, 2, 1);
    SUBSTEP(cc+1, 1, accB, accA, cc+3, 3, 2, 1);
    SUBSTEP(cc+2, 2, accA, accB, cc+4, 0, 2, 1);
    SUBSTEP(cc+3, 3, accB, accA, cc+5, 1, 2, 1);
  }
  // peeled tail: chunks 124..127 (stages 126,127; final waits drain)
  SUBSTEP(124, 0, accA, accB, 126, 2, 2, 1);
  SUBSTEP(125, 1, accB, accA, 127, 3, 2, 1);
  SUBSTEP(126, 2, accA, accB, 0, 0, 2, 0);
  SUBSTEP(127, 3, accB, accA, 0, 0, 0, 0);
  { // final epilogue: chunk 127 lives in accB
    const unsigned pcolu = (unsigned)(qtr*2048 + 127*16 + lp);
    #pragma unroll
    for (int s = 0; s < 16; ++s) {
      const int mb = s>>2, r = s&3;
      unsigned us = (__float_as_uint(accB[mb][r]) & 0xFFFFE000u) | pcolu;
      unsigned o1 = m1u[mb][r];
      m2u[mb][r] = umin_(m2u[mb][r], umax_(o1, us));
      m1u[mb][r] = umin_(o1, us);
    }
  }
  #undef SUBSTEP
  #undef STAGE

  // merge across the 16 lp-lanes of each quad (waves own disjoint rows)
  #pragma unroll
  for (int off = 1; off <= 8; off <<= 1) {
    #pragma unroll
    for (int mb=0;mb<4;++mb)
      #pragma unroll
      for (int r=0;r<4;++r) {
        unsigned o1 = (unsigned)__shfl_xor((int)m1u[mb][r], off);
        unsigned o2 = (unsigned)__shfl_xor((int)m2u[mb][r], off);
        unsigned hi = umax_(m1u[mb][r], o1);
        m2u[mb][r] = umin_(umin_(m2u[mb][r], o2), hi);
        m1u[mb][r] = umin_(m1u[mb][r], o1);
      }
  }
  if (lp == 0) {
    #pragma unroll
    for (int mb=0;mb<4;++mb)
      #pragma unroll
      for (int r=0;r<4;++r) {
        int row = rowbase + mb*16 + q*4 + r;
        m1q[qtr*NPTS + row] = m1u[mb][r];
        m2q[qtr*NPTS + row] = m2u[mb][r];
      }
  }
}

// ------------------------------------- merge 4 quarters, write idx/m1s, flag
// All values are packed acc-domain (negative floats): umin == min score.
// s2-s1 < W  <=>  a1-a2 < W/2.
__global__ void k_merge(const unsigned* __restrict__ m1q, const unsigned* __restrict__ m2q,
                        int* __restrict__ idx, float* __restrict__ m1s,
                        int* __restrict__ flaglist, int* __restrict__ flagcount)
{
  const int row = blockIdx.x*256 + threadIdx.x;   // 128 blocks
  unsigned u0 = m1q[row], u1 = m1q[NPTS + row], u2 = m1q[2*NPTS + row], u3 = m1q[3*NPTS + row];
  unsigned w0 = m2q[row], w1 = m2q[NPTS + row], w2 = m2q[2*NPTS + row], w3 = m2q[3*NPTS + row];
  unsigned a = umin_(u0,u1), b = umax_(u0,u1), cx = umin_(u2,u3), d = umax_(u2,u3);
  unsigned m1g = umin_(a, cx);
  unsigned sec = umin_(umax_(a, cx), umin_(b, d));
  unsigned m2g = umin_(umin_(umin_(w0,w1), umin_(w2,w3)), sec);
  float m1f = __uint_as_float(m1g & 0xFFFFE000u);   // = -s1/2
  float m2f = __uint_as_float(m2g & 0xFFFFE000u);   // = -s2/2
  idx[row] = (int)(m1g & 0x1FFFu);
  m1s[row] = m1f;
  if (m1f - m2f < 0.5f*WINDOW) {
    int p = atomicAdd(flagcount, 1);
    if (p < FLAGCAP) flaglist[p] = row;
  }
}

// -------------------------------- P2: rescan flagged rows, collect candidates
// grid 512 = 16 batch-slots x 32 K-slices (8 chunks each), dbuf LDS staging.
// acc-domain: candidate iff acc > m1s - W/2  (<=> s < s1 + W).
__launch_bounds__(256, 2)
__global__ void k_rescan(const float* __restrict__ X, const _Float16* __restrict__ EhP,
                         const float* __restrict__ e2n, const float* __restrict__ m1s,
                         const int* __restrict__ flaglist, const int* __restrict__ flagcount,
                         int* __restrict__ ccounts, int* __restrict__ candbuf)
{
  __shared__ __align__(16) _Float16 Bsh[2][8192];
  const int tid = threadIdx.x, lane = tid & 63, wid = tid >> 6;
  const int q = lane >> 4, lp = lane & 15;
  const int slice = blockIdx.x & 31, bslot = blockIdx.x >> 5;
  const int stag = wid*1024 + lane*16;
  int cnt = *flagcount; if (cnt > FLAGCAP) cnt = FLAGCAP;

  for (int batch = bslot; batch*256 < cnt; batch += 16) {
    const int base = batch*256 + wid*64;
    { // issue chunk slice*8 staging (overlaps A build)
      const char* g = (const char*)(EhP + (size_t)(slice*8)*8192);
      #pragma unroll
      for (int r = 0; r < 4; ++r)
        gl_lds16(g + r*4096 + stag, (char*)&Bsh[0][0] + r*4096 + stag);
    }
    int ga[4];
    #pragma unroll
    for (int mb=0;mb<4;++mb) {
      int fi = base + mb*16 + lp;
      ga[mb] = (fi < cnt) ? flaglist[fi] : 0;
    }
    float thr[4][4]; int fis[4][4];
    #pragma unroll
    for (int mb=0;mb<4;++mb)
      #pragma unroll
      for (int r=0;r<4;++r) {
        int fi = base + mb*16 + q*4 + r;
        fis[mb][r] = fi;
        if (fi < cnt) thr[mb][r] = m1s[flaglist[fi]] - 0.5f*WINDOW;
        else          thr[mb][r] = 3.0e38f;      // acc is negative: never true
      }
    half8 af[4][8];
    #pragma unroll
    for (int mb = 0; mb < 4; ++mb) {
      const float* xr = X + (size_t)ga[mb]*DDIM;
      #pragma unroll
      for (int st = 0; st < 8; ++st) {
        const float* p = xr + st*32 + q*8;
        float4 v0 = *(const float4*)p;
        float4 v1 = *(const float4*)(p + 4);
        half8 h;
        h[0]=(_Float16)(16.f*v0.x); h[1]=(_Float16)(16.f*v0.y);
        h[2]=(_Float16)(16.f*v0.z); h[3]=(_Float16)(16.f*v0.w);
        h[4]=(_Float16)(16.f*v1.x); h[5]=(_Float16)(16.f*v1.y);
        h[6]=(_Float16)(16.f*v1.z); h[7]=(_Float16)(16.f*v1.w);
        af[mb][st] = h;
      }
    }
    float ezn0 = e2n[slice*256 + lp];
    float ezn1 = e2n[slice*256 + 16 + lp];
    for (int j = 0; j < 8; ++j) {
      const int cur = j & 1;
      const float ez0 = ezn0, ez1 = ezn1;
      __syncthreads();
      if (j + 1 < 8) {
        const char* g = (const char*)(EhP + (size_t)(slice*8 + j + 1)*8192);
        #pragma unroll
        for (int r = 0; r < 4; ++r)
          gl_lds16(g + r*4096 + stag, (char*)&Bsh[cur^1][0] + r*4096 + stag);
        ezn0 = e2n[slice*256 + (j+1)*32 + lp];
        ezn1 = e2n[slice*256 + (j+1)*32 + 16 + lp];
      }
      f32x4 acc[4][2];
      #pragma unroll
      for (int mb=0;mb<4;++mb) {
        f32x4 a0 = {ez0, ez0, ez0, ez0};
        f32x4 a1 = {ez1, ez1, ez1, ez1};
        acc[mb][0] = a0; acc[mb][1] = a1;
      }
      #pragma unroll
      for (int st = 0; st < 8; ++st) {
        half8 bf[2];
        bf[0] = *(const half8*)(&Bsh[cur][(st*2+0)*512 + lane*8]);
        bf[1] = *(const half8*)(&Bsh[cur][(st*2+1)*512 + lane*8]);
        #pragma unroll
        for (int nb = 0; nb < 2; ++nb)
          #pragma unroll
          for (int mb = 0; mb < 4; ++mb)
            acc[mb][nb] = __builtin_amdgcn_mfma_f32_16x16x32_f16(af[mb][st], bf[nb], acc[mb][nb], 0, 0, 0);
      }
      const int c = slice*8 + j;
      #pragma unroll
      for (int nb = 0; nb < 2; ++nb) {
        const int col = c*32 + nb*16 + lp;
        #pragma unroll
        for (int mb = 0; mb < 4; ++mb)
          #pragma unroll
          for (int r = 0; r < 4; ++r) {
            if (acc[mb][nb][r] > thr[mb][r]) {
              int fi = fis[mb][r];
              int slot = atomicAdd(&ccounts[fi], 1);
              if (slot < CANDCAP) candbuf[fi*CANDCAP + slot] = col;
            }
          }
      }
    }
    __syncthreads();   // protect Bsh before next batch's preload
  }
}

// -------------------------------------- P3: exact fp64 argmin over candidates
__global__ void k_exact(const float* __restrict__ X, const float* __restrict__ Et,
                        const int* __restrict__ flaglist, const int* __restrict__ flagcount,
                        const int* __restrict__ ccounts, const int* __restrict__ candbuf,
                        int* __restrict__ idx)
{
  int cnt = *flagcount; if (cnt > FLAGCAP) cnt = FLAGCAP;
  const int lane = threadIdx.x & 63;
  const int w = blockIdx.x*4 + (threadIdx.x >> 6);      // 256 blocks -> 1024 waves
  for (int i = w; i < cnt; i += 1024) {
    const int g = flaglist[i];
    const int cc = ccounts[i];
    double best = 1.0e300; int bestk = 0x7FFFFFFF;
    if (cc <= CANDCAP) {
      float4 xv = *(const float4*)(X + (size_t)g*DDIM + lane*4);
      for (int c = 0; c < cc; ++c) {
        int k = candbuf[i*CANDCAP + c];
        float4 ev = *(const float4*)(Et + (size_t)k*DDIM + lane*4);
        double d0 = (double)xv.x - (double)ev.x, d1 = (double)xv.y - (double)ev.y;
        double d2 = (double)xv.z - (double)ev.z, d3 = (double)xv.w - (double)ev.w;
        double s = d0*d0 + d1*d1 + d2*d2 + d3*d3;
        #pragma unroll
        for (int off = 1; off < 64; off <<= 1) s += __shfl_xor(s, off);
        if (s < best || (s == best && k < bestk)) { best = s; bestk = k; }
      }
    } else {  // candbuf overflow: full exact scan (statistically ~never)
      double bb = 1.0e300; int bk = 0x7FFFFFFF;
      for (int k = lane; k < KCOD; k += 64) {
        double s = 0.0;
        for (int d = 0; d < DDIM; ++d) {
          double df = (double)X[(size_t)g*DDIM + d] - (double)Et[(size_t)k*DDIM + d];
          s += df*df;
        }
        if (s < bb || (s == bb && k < bk)) { bb = s; bk = k; }
      }
      #pragma unroll
      for (int off = 1; off < 64; off <<= 1) {
        double ob = __shfl_xor(bb, off); int ok = __shfl_xor(bk, off);
        if (ob < bb || (ob == bb && ok < bk)) { bb = ob; bk = ok; }
      }
      best = bb; bestk = bk;
    }
    if (lane == 0 && bestk != 0x7FFFFFFF) idx[g] = bestk;
  }
}

// -------------------------------------------------- P4: gather output + loss
__global__ void k_gather(const float* __restrict__ X, const float* __restrict__ Et,
                         const int* __restrict__ idx, float* __restrict__ out)
{
  const int lane = threadIdx.x & 63, wid = threadIdx.x >> 6;
  float lsum = 0.0f;
  for (int i = 0; i < 16; ++i) {
    int n = blockIdx.x*64 + i*4 + wid;
    int k = idx[n];
    float4 xv = *(const float4*)(X  + (size_t)n*DDIM + lane*4);
    float4 ev = *(const float4*)(Et + (size_t)k*DDIM + lane*4);
    *(float4*)(out + (size_t)n*DDIM + lane*4) = ev;   // ST fwd value == quantized
    float d0 = ev.x-xv.x, d1 = ev.y-xv.y, d2 = ev.z-xv.z, d3 = ev.w-xv.w;
    lsum += d0*d0 + d1*d1 + d2*d2 + d3*d3;
  }
  #pragma unroll
  for (int off = 1; off < 64; off <<= 1) lsum += __shfl_xor(lsum, off);
  if (lane == 0) atomicAdd(out + (size_t)NELEM, lsum * (1.25f/8388608.0f));
}

// ================================ launch ======================================
extern "C" void kernel_launch(void* const* d_in, const int* in_sizes, int n_in,
                              void* d_out, int out_size, void* d_ws, size_t ws_size,
                              hipStream_t stream)
{
  const float* X = (const float*)d_in[0];   // [32768][256]
  const float* E = (const float*)d_in[1];   // [256][8192]
  float* out = (float*)d_out;               // [8388608 quantized][1 loss]
  char* ws = (char*)d_ws;

  float*     Et        = (float*)(ws);                               // 8 MB
  _Float16*  EhP       = (_Float16*)(ws + 8388608);                  // 4 MB
  float*     e2n       = (float*)(ws + 12582912);                    // 32 KB
  unsigned*  m1q       = (unsigned*)(ws + 12615680);                 // 512 KB
  unsigned*  m2q       = (unsigned*)(ws + 13139968);                 // 512 KB
  float*     m1s       = (float*)(ws + 13664256);                    // 128 KB
  int*       idx       = (int*)(ws + 13795328);                      // 128 KB
  int*       flaglist  = (int*)(ws + 13926400);                      // 64 KB
  int*       ccounts   = (int*)(ws + 13991936);                      // 64 KB
  int*       candbuf   = (int*)(ws + 14057472);                      // 1 MB
  int*       flagcount = (int*)(ws + 15106048);                      // 4 B
  if (ws_size < (size_t)15106052) return;

  dim3 B(256);
  k_prepE <<<dim3(512),  B, 0, stream>>>(E, EhP, Et);
  k_e2z   <<<dim3(2048), B, 0, stream>>>(Et, e2n, ccounts, flagcount, out + NELEM);
  k_screen<<<dim3(512),  B, 0, stream>>>(X, EhP, e2n, m1q, m2q);
  k_merge <<<dim3(128),  B, 0, stream>>>(m1q, m2q, idx, m1s, flaglist, flagcount);
  k_rescan<<<dim3(512),  B, 0, stream>>>(X, EhP, e2n, m1s, flaglist, flagcount, ccounts, candbuf);
  k_exact <<<dim3(256),  B, 0, stream>>>(X, Et, flaglist, flagcount, ccounts, candbuf, idx);
  k_gather<<<dim3(512),  B, 0, stream>>>(X, Et, idx, out);
}

// Round 8
// 270.758 us; speedup vs baseline: 1.4170x; 1.0820x over previous
//
#include <hip/hip_runtime.h>
#include <cstdint>
#include <cstddef>

// ================= VQ layer: N=32768 pts, D=256, K=8192 codes ==================
// prepE (LDS-transpose, 512 blocks) -> e2z (from Et, 2048 blocks, + zero) ->
// screen (f16 MFMA, counted-vmcnt 4-buffer LDS ring, raw s_barrier without
// vmcnt(0) drain, deferred epilogue) -> merge (block-aggregated flag atomics)
// -> rescan (dbuf) -> exact (cc==1 skip) -> gather (block-reduced loss atomic)
#define NPTS    32768
#define DDIM    256
#define KCOD    8192
#define NELEM   8388608           // NPTS*DDIM
#define BIAS    4096.0f
#define WINDOW  8.0f              // ~11 sigma of f16-score error model
#define FLAGCAP 16384
#define CANDCAP 16

typedef _Float16 half8 __attribute__((ext_vector_type(8)));
typedef float    f32x4 __attribute__((ext_vector_type(4)));

__device__ __forceinline__ unsigned umin_(unsigned a, unsigned b){ return a<b?a:b; }
__device__ __forceinline__ unsigned umax_(unsigned a, unsigned b){ return a>b?a:b; }

// async global->LDS, 16B per lane; lds dest linear in lane order
__device__ __forceinline__ void gl_lds16(const void* g, void* l) {
  __builtin_amdgcn_global_load_lds(
      (const __attribute__((address_space(1))) unsigned int*)g,
      (__attribute__((address_space(3))) unsigned int*)l, 16, 0, 0);
}

// --------------------------------------------------------------- prepE
// 512 blocks = 128 colgroups x 4 dsteps; per block: 64 cols x 64 d tile.
// EhP elem idx = chunk32*8192 + (st*2+nb)*512 + (q*16+n16)*8 + j
//   where col = chunk32*32 + nb*16 + n16, d = st*32 + q*8 + j.
__global__ void k_prepE(const float* __restrict__ E, _Float16* __restrict__ EhP,
                        float* __restrict__ Et) {
  __shared__ float T[64][65];
  const int tid = threadIdx.x;
  const int cg = blockIdx.x & 127, dstep = blockIdx.x >> 7;
  const int k0 = cg*64, c0 = cg*2;
  { // load 64 d x 64 k, coalesced within 256B rows
    const int kl = tid & 63, wq = tid >> 6;
    #pragma unroll
    for (int rr = 0; rr < 16; ++rr) {
      int dl = rr*4 + wq;
      T[dl][kl] = E[(size_t)(dstep*64 + dl)*KCOD + k0 + kl];
    }
  }
  __syncthreads();
  { // Et rows: [k][d] contiguous
    const int kk = tid >> 2, fq = tid & 3;
    #pragma unroll
    for (int iter = 0; iter < 4; ++iter) {
      int db = iter*16 + fq*4;
      float4 v = make_float4(T[db][kk], T[db+1][kk], T[db+2][kk], T[db+3][kk]);
      *(float4*)(Et + (size_t)(k0+kk)*DDIM + dstep*64 + db) = v;
    }
  }
  { // EhP frag-order (512 groups of 8 this dstep)
    #pragma unroll
    for (int gi = 0; gi < 2; ++gi) {
      int g = gi*256 + tid;
      int n16 = g & 15, q = (g>>4)&3, nb = (g>>6)&1, stp = (g>>7)&1, ch = (g>>8)&1;
      int st = dstep*2 + stp;
      int kl2 = ch*32 + nb*16 + n16;
      int dl = stp*32 + q*8;
      half8 h;
      #pragma unroll
      for (int j = 0; j < 8; ++j) h[j] = (_Float16)(16.0f * T[dl + j][kl2]);
      *(half8*)(EhP + (size_t)(c0+ch)*8192 + (st*2+nb)*512 + (q*16+n16)*8) = h;
    }
  }
}

// --- e2n[k] = -0.5*(256*||E_k||^2 + BIAS)  (acc-domain init value) + zeroing
__global__ void k_e2z(const float* __restrict__ Et, float* __restrict__ e2n,
                      int* __restrict__ ccounts, int* __restrict__ flagcount,
                      float* __restrict__ out_loss) {
  const int lane = threadIdx.x & 63, wid = threadIdx.x >> 6;
  const int k = blockIdx.x*4 + wid;                     // 2048 blocks
  float4 v = *((const float4*)(Et + (size_t)k*DDIM) + lane);
  float s = v.x*v.x + v.y*v.y + v.z*v.z + v.w*v.w;
  #pragma unroll
  for (int off = 1; off < 64; off <<= 1) s += __shfl_xor(s, off);
  if (lane == 0) e2n[k] = fmaf(-128.0f, s, -0.5f*BIAS);
  int t = blockIdx.x*256 + threadIdx.x;
  if (t < FLAGCAP) ccounts[t] = 0;
  if (t == 0) { *flagcount = 0; *out_loss = 0.0f; }
}

// --------------------------------------------------------- P1: f16 MFMA screen
// (unchanged from R5: best measured variant, 139 us)
__launch_bounds__(256, 2)
__global__ void k_screen(const float* __restrict__ X, const _Float16* __restrict__ EhP,
                         const float* __restrict__ e2n, unsigned* __restrict__ m1q,
                         unsigned* __restrict__ m2q)
{
  __shared__ __align__(16) _Float16 Bsh[4][4096];   // 4 x 8 KB ring
  __shared__ __align__(16) float    E2s[2048];      // 8 KB e2n quarter
  const int tid = threadIdx.x;
  const int lane = tid & 63, wid = tid >> 6;
  const int q = lane >> 4, lp = lane & 15;
  const int qtr = blockIdx.x & 3, rg = blockIdx.x >> 2;
  const int rowbase = rg*256 + wid*64;
  const int lb = lane*16;
  const char* gq = (const char*)EhP + (size_t)qtr*1048576;   // 1 MB quarter

  // A fragments FIRST (oldest in vm queue; loop's vmcnt(2) covers them)
  half8 af[4][8];
  #pragma unroll
  for (int mb = 0; mb < 4; ++mb) {
    const float* xr = X + (size_t)(rowbase + mb*16 + lp)*DDIM;
    #pragma unroll
    for (int st = 0; st < 8; ++st) {
      const float* p = xr + st*32 + q*8;
      float4 v0 = *(const float4*)p;
      float4 v1 = *(const float4*)(p + 4);
      half8 h;
      h[0]=(_Float16)(16.f*v0.x); h[1]=(_Float16)(16.f*v0.y);
      h[2]=(_Float16)(16.f*v0.z); h[3]=(_Float16)(16.f*v0.w);
      h[4]=(_Float16)(16.f*v1.x); h[5]=(_Float16)(16.f*v1.y);
      h[6]=(_Float16)(16.f*v1.z); h[7]=(_Float16)(16.f*v1.w);
      af[mb][st] = h;
    }
  }

  // chunk cc staging: 8 KB = 8 slabs of 1 KB; wave wid stages slabs 2wid,2wid+1
  #define STAGE(cc, B) do {                                                   \
    const char* gs_ = gq + (size_t)((cc)>>1)*16384 + (size_t)((cc)&1)*1024    \
                         + wid*4096;                                          \
    char* ds_ = (char*)&Bsh[B][0] + wid*2048;                                 \
    gl_lds16(gs_ + lb, ds_ + lb);                                             \
    gl_lds16(gs_ + 2048 + lb, ds_ + 1024 + lb);                               \
  } while (0)

  { // stage e2n quarter (wave wid: slabs 2wid, 2wid+1), then chunks 0,1
    const char* ge = (const char*)(e2n + (size_t)qtr*2048) + wid*2048;
    gl_lds16(ge + lb, (char*)E2s + wid*2048 + lb);
    gl_lds16(ge + 1024 + lb, (char*)E2s + wid*2048 + 1024 + lb);
    STAGE(0, 0);
    STAGE(1, 1);
  }

  unsigned m1u[4][4], m2u[4][4];
  #pragma unroll
  for (int mb=0;mb<4;++mb)
    #pragma unroll
    for (int r=0;r<4;++r) { m1u[mb][r]=0xFFFFFFFFu; m2u[mb][r]=0xFFFFFFFFu; }

  f32x4 accA[4], accB[4];
  const float NEGINF = __uint_as_float(0xFF800000u);
  #pragma unroll
  for (int mb=0;mb<4;++mb) { f32x4 z = {NEGINF,NEGINF,NEGINF,NEGINF}; accB[mb] = z; }

  #define SUBSTEP(cc, BUF, ACC, PACC, STCC, SBUF, WAITN, DO_STAGE) do {       \
    asm volatile("s_waitcnt vmcnt(" #WAITN ")" ::: "memory");                 \
    __builtin_amdgcn_s_barrier();                                             \
    __builtin_amdgcn_sched_barrier(0);                                        \
    if (DO_STAGE) { STAGE(STCC, SBUF); }                                      \
    const float ez_ = E2s[(cc)*16 + lp];                                      \
    _Pragma("unroll")                                                         \
    for (int mb_=0;mb_<4;++mb_){ f32x4 a_={ez_,ez_,ez_,ez_}; ACC[mb_]=a_; }   \
    const unsigned pcolu_ = (unsigned)(qtr*2048 + ((cc)-1)*16 + lp);          \
    __builtin_amdgcn_s_setprio(1);                                            \
    _Pragma("unroll")                                                         \
    for (int st_=0; st_<8; ++st_) {                                           \
      half8 bf_ = *(const half8*)((const char*)&Bsh[BUF][0] + st_*1024 + lb); \
      _Pragma("unroll")                                                       \
      for (int mb_=0;mb_<4;++mb_)                                             \
        ACC[mb_] = __builtin_amdgcn_mfma_f32_16x16x32_f16(af[mb_][st_], bf_,  \
                                                          ACC[mb_], 0, 0, 0); \
      _Pragma("unroll")                                                       \
      for (int k_=0;k_<2;++k_) {                                              \
        const int s_ = st_*2 + k_, mbp_ = s_>>2, rp_ = s_&3;                  \
        unsigned us_ = (__float_as_uint(PACC[mbp_][rp_]) & 0xFFFFE000u) | pcolu_; \
        unsigned o1_ = m1u[mbp_][rp_];                                        \
        m2u[mbp_][rp_] = umin_(m2u[mbp_][rp_], umax_(o1_, us_));              \
        m1u[mbp_][rp_] = umin_(o1_, us_);                                     \
      }                                                                       \
    }                                                                         \
    __builtin_amdgcn_s_setprio(0);                                            \
  } while (0)

  #pragma unroll 1
  for (int k = 0; k < 31; ++k) {
    const int cc = k*4;
    SUBSTEP(cc+0, 0, accA, accB, cc+2, 2, 2, 1);
    SUBSTEP(cc+1, 1, accB, accA, cc+3, 3, 2, 1);
    SUBSTEP(cc+2, 2, accA, accB, cc+4, 0, 2, 1);
    SUBSTEP(cc+3, 3, accB, accA, cc+5, 1, 2, 1);
  }
  SUBSTEP(124, 0, accA, accB, 126, 2, 2, 1);
  SUBSTEP(125, 1, accB, accA, 127, 3, 2, 1);
  SUBSTEP(126, 2, accA, accB, 0, 0, 2, 0);
  SUBSTEP(127, 3, accB, accA, 0, 0, 0, 0);
  { // final epilogue: chunk 127 lives in accB
    const unsigned pcolu = (unsigned)(qtr*2048 + 127*16 + lp);
    #pragma unroll
    for (int s = 0; s < 16; ++s) {
      const int mb = s>>2, r = s&3;
      unsigned us = (__float_as_uint(accB[mb][r]) & 0xFFFFE000u) | pcolu;
      unsigned o1 = m1u[mb][r];
      m2u[mb][r] = umin_(m2u[mb][r], umax_(o1, us));
      m1u[mb][r] = umin_(o1, us);
    }
  }
  #undef SUBSTEP
  #undef STAGE

  // merge across the 16 lp-lanes of each quad (waves own disjoint rows)
  #pragma unroll
  for (int off = 1; off <= 8; off <<= 1) {
    #pragma unroll
    for (int mb=0;mb<4;++mb)
      #pragma unroll
      for (int r=0;r<4;++r) {
        unsigned o1 = (unsigned)__shfl_xor((int)m1u[mb][r], off);
        unsigned o2 = (unsigned)__shfl_xor((int)m2u[mb][r], off);
        unsigned hi = umax_(m1u[mb][r], o1);
        m2u[mb][r] = umin_(umin_(m2u[mb][r], o2), hi);
        m1u[mb][r] = umin_(m1u[mb][r], o1);
      }
  }
  if (lp == 0) {
    #pragma unroll
    for (int mb=0;mb<4;++mb)
      #pragma unroll
      for (int r=0;r<4;++r) {
        int row = rowbase + mb*16 + q*4 + r;
        m1q[qtr*NPTS + row] = m1u[mb][r];
        m2q[qtr*NPTS + row] = m2u[mb][r];
      }
  }
}

// ------------------------------------- merge 4 quarters, write idx/m1s, flag
// Packed acc-domain values (negative floats): umin == min score.
// BLOCK-AGGREGATED flag emission: ballot/popcount per wave, one atomicAdd
// per block (128 total) instead of one per flagged row.
__global__ void k_merge(const unsigned* __restrict__ m1q, const unsigned* __restrict__ m2q,
                        int* __restrict__ idx, float* __restrict__ m1s,
                        int* __restrict__ flaglist, int* __restrict__ flagcount)
{
  __shared__ int wbase[4];
  const int tid = threadIdx.x, lane = tid & 63, wid = tid >> 6;
  const int row = blockIdx.x*256 + tid;   // 128 blocks
  unsigned u0 = m1q[row], u1 = m1q[NPTS + row], u2 = m1q[2*NPTS + row], u3 = m1q[3*NPTS + row];
  unsigned w0 = m2q[row], w1 = m2q[NPTS + row], w2 = m2q[2*NPTS + row], w3 = m2q[3*NPTS + row];
  unsigned a = umin_(u0,u1), b = umax_(u0,u1), cx = umin_(u2,u3), d = umax_(u2,u3);
  unsigned m1g = umin_(a, cx);
  unsigned sec = umin_(umax_(a, cx), umin_(b, d));
  unsigned m2g = umin_(umin_(umin_(w0,w1), umin_(w2,w3)), sec);
  float m1f = __uint_as_float(m1g & 0xFFFFE000u);   // = -s1/2
  float m2f = __uint_as_float(m2g & 0xFFFFE000u);   // = -s2/2
  idx[row] = (int)(m1g & 0x1FFFu);
  m1s[row] = m1f;
  const bool f = (m1f - m2f < 0.5f*WINDOW);
  unsigned long long bal = __ballot(f);
  if (lane == 0) wbase[wid] = __popcll(bal);
  __syncthreads();
  if (tid == 0) {
    int t0 = wbase[0], t1 = wbase[1], t2 = wbase[2], t3 = wbase[3];
    int p = atomicAdd(flagcount, t0 + t1 + t2 + t3);
    wbase[0] = p; wbase[1] = p + t0; wbase[2] = p + t0 + t1; wbase[3] = p + t0 + t1 + t2;
  }
  __syncthreads();
  if (f) {
    int pos = wbase[wid] + __popcll(bal & ((1ull << lane) - 1ull));
    if (pos < FLAGCAP) flaglist[pos] = row;
  }
}

// -------------------------------- P2: rescan flagged rows, collect candidates
// grid 512 = 16 batch-slots x 32 K-slices (8 chunks each), dbuf LDS staging.
// acc-domain: candidate iff acc > m1s - W/2  (<=> s < s1 + W).
__launch_bounds__(256, 2)
__global__ void k_rescan(const float* __restrict__ X, const _Float16* __restrict__ EhP,
                         const float* __restrict__ e2n, const float* __restrict__ m1s,
                         const int* __restrict__ flaglist, const int* __restrict__ flagcount,
                         int* __restrict__ ccounts, int* __restrict__ candbuf)
{
  __shared__ __align__(16) _Float16 Bsh[2][8192];
  const int tid = threadIdx.x, lane = tid & 63, wid = tid >> 6;
  const int q = lane >> 4, lp = lane & 15;
  const int slice = blockIdx.x & 31, bslot = blockIdx.x >> 5;
  const int stag = wid*1024 + lane*16;
  int cnt = *flagcount; if (cnt > FLAGCAP) cnt = FLAGCAP;

  for (int batch = bslot; batch*256 < cnt; batch += 16) {
    const int base = batch*256 + wid*64;
    { // issue chunk slice*8 staging (overlaps A build)
      const char* g = (const char*)(EhP + (size_t)(slice*8)*8192);
      #pragma unroll
      for (int r = 0; r < 4; ++r)
        gl_lds16(g + r*4096 + stag, (char*)&Bsh[0][0] + r*4096 + stag);
    }
    int ga[4];
    #pragma unroll
    for (int mb=0;mb<4;++mb) {
      int fi = base + mb*16 + lp;
      ga[mb] = (fi < cnt) ? flaglist[fi] : 0;
    }
    float thr[4][4]; int fis[4][4];
    #pragma unroll
    for (int mb=0;mb<4;++mb)
      #pragma unroll
      for (int r=0;r<4;++r) {
        int fi = base + mb*16 + q*4 + r;
        fis[mb][r] = fi;
        if (fi < cnt) thr[mb][r] = m1s[flaglist[fi]] - 0.5f*WINDOW;
        else          thr[mb][r] = 3.0e38f;      // acc is negative: never true
      }
    half8 af[4][8];
    #pragma unroll
    for (int mb = 0; mb < 4; ++mb) {
      const float* xr = X + (size_t)ga[mb]*DDIM;
      #pragma unroll
      for (int st = 0; st < 8; ++st) {
        const float* p = xr + st*32 + q*8;
        float4 v0 = *(const float4*)p;
        float4 v1 = *(const float4*)(p + 4);
        half8 h;
        h[0]=(_Float16)(16.f*v0.x); h[1]=(_Float16)(16.f*v0.y);
        h[2]=(_Float16)(16.f*v0.z); h[3]=(_Float16)(16.f*v0.w);
        h[4]=(_Float16)(16.f*v1.x); h[5]=(_Float16)(16.f*v1.y);
        h[6]=(_Float16)(16.f*v1.z); h[7]=(_Float16)(16.f*v1.w);
        af[mb][st] = h;
      }
    }
    float ezn0 = e2n[slice*256 + lp];
    float ezn1 = e2n[slice*256 + 16 + lp];
    for (int j = 0; j < 8; ++j) {
      const int cur = j & 1;
      const float ez0 = ezn0, ez1 = ezn1;
      __syncthreads();
      if (j + 1 < 8) {
        const char* g = (const char*)(EhP + (size_t)(slice*8 + j + 1)*8192);
        #pragma unroll
        for (int r = 0; r < 4; ++r)
          gl_lds16(g + r*4096 + stag, (char*)&Bsh[cur^1][0] + r*4096 + stag);
        ezn0 = e2n[slice*256 + (j+1)*32 + lp];
        ezn1 = e2n[slice*256 + (j+1)*32 + 16 + lp];
      }
      f32x4 acc[4][2];
      #pragma unroll
      for (int mb=0;mb<4;++mb) {
        f32x4 a0 = {ez0, ez0, ez0, ez0};
        f32x4 a1 = {ez1, ez1, ez1, ez1};
        acc[mb][0] = a0; acc[mb][1] = a1;
      }
      #pragma unroll
      for (int st = 0; st < 8; ++st) {
        half8 bf[2];
        bf[0] = *(const half8*)(&Bsh[cur][(st*2+0)*512 + lane*8]);
        bf[1] = *(const half8*)(&Bsh[cur][(st*2+1)*512 + lane*8]);
        #pragma unroll
        for (int nb = 0; nb < 2; ++nb)
          #pragma unroll
          for (int mb = 0; mb < 4; ++mb)
            acc[mb][nb] = __builtin_amdgcn_mfma_f32_16x16x32_f16(af[mb][st], bf[nb], acc[mb][nb], 0, 0, 0);
      }
      const int c = slice*8 + j;
      #pragma unroll
      for (int nb = 0; nb < 2; ++nb) {
        const int col = c*32 + nb*16 + lp;
        #pragma unroll
        for (int mb = 0; mb < 4; ++mb)
          #pragma unroll
          for (int r = 0; r < 4; ++r) {
            if (acc[mb][nb][r] > thr[mb][r]) {
              int fi = fis[mb][r];
              int slot = atomicAdd(&ccounts[fi], 1);
              if (slot < CANDCAP) candbuf[fi*CANDCAP + slot] = col;
            }
          }
      }
    }
    __syncthreads();   // protect Bsh before next batch's preload
  }
}

// -------------------------------------- P3: exact fp64 argmin over candidates
// cc==1 fast-skip: the lone candidate is the screen argmin already in idx[g].
__global__ void k_exact(const float* __restrict__ X, const float* __restrict__ Et,
                        const int* __restrict__ flaglist, const int* __restrict__ flagcount,
                        const int* __restrict__ ccounts, const int* __restrict__ candbuf,
                        int* __restrict__ idx)
{
  int cnt = *flagcount; if (cnt > FLAGCAP) cnt = FLAGCAP;
  const int lane = threadIdx.x & 63;
  const int w = blockIdx.x*4 + (threadIdx.x >> 6);      // 256 blocks -> 1024 waves
  for (int i = w; i < cnt; i += 1024) {
    const int cc = ccounts[i];
    if (cc <= 1) continue;                              // screen argmin stands
    const int g = flaglist[i];
    double best = 1.0e300; int bestk = 0x7FFFFFFF;
    if (cc <= CANDCAP) {
      float4 xv = *(const float4*)(X + (size_t)g*DDIM + lane*4);
      for (int c = 0; c < cc; ++c) {
        int k = candbuf[i*CANDCAP + c];
        float4 ev = *(const float4*)(Et + (size_t)k*DDIM + lane*4);
        double d0 = (double)xv.x - (double)ev.x, d1 = (double)xv.y - (double)ev.y;
        double d2 = (double)xv.z - (double)ev.z, d3 = (double)xv.w - (double)ev.w;
        double s = d0*d0 + d1*d1 + d2*d2 + d3*d3;
        #pragma unroll
        for (int off = 1; off < 64; off <<= 1) s += __shfl_xor(s, off);
        if (s < best || (s == best && k < bestk)) { best = s; bestk = k; }
      }
    } else {  // candbuf overflow: full exact scan (statistically ~never)
      double bb = 1.0e300; int bk = 0x7FFFFFFF;
      for (int k = lane; k < KCOD; k += 64) {
        double s = 0.0;
        for (int d = 0; d < DDIM; d += 4) {
          float4 xv = *(const float4*)(X + (size_t)g*DDIM + d);
          float4 ev = *(const float4*)(Et + (size_t)k*DDIM + d);
          double d0 = (double)xv.x - (double)ev.x, d1 = (double)xv.y - (double)ev.y;
          double d2 = (double)xv.z - (double)ev.z, d3 = (double)xv.w - (double)ev.w;
          s += d0*d0 + d1*d1 + d2*d2 + d3*d3;
        }
        if (s < bb || (s == bb && k < bk)) { bb = s; bk = k; }
      }
      #pragma unroll
      for (int off = 1; off < 64; off <<= 1) {
        double ob = __shfl_xor(bb, off); int ok = __shfl_xor(bk, off);
        if (ob < bb || (ob == bb && ok < bk)) { bb = ob; bk = ok; }
      }
      best = bb; bestk = bk;
    }
    if (lane == 0 && bestk != 0x7FFFFFFF) idx[g] = bestk;
  }
}

// -------------------------------------------------- P4: gather output + loss
// Loss: LDS-reduce the 4 wave sums -> ONE atomicAdd per block (512 total).
__global__ void k_gather(const float* __restrict__ X, const float* __restrict__ Et,
                         const int* __restrict__ idx, float* __restrict__ out)
{
  __shared__ float ls[4];
  const int tid = threadIdx.x, lane = tid & 63, wid = tid >> 6;
  float lsum = 0.0f;
  for (int i = 0; i < 16; ++i) {
    int n = blockIdx.x*64 + i*4 + wid;
    int k = idx[n];
    float4 xv = *(const float4*)(X  + (size_t)n*DDIM + lane*4);
    float4 ev = *(const float4*)(Et + (size_t)k*DDIM + lane*4);
    *(float4*)(out + (size_t)n*DDIM + lane*4) = ev;   // ST fwd value == quantized
    float d0 = ev.x-xv.x, d1 = ev.y-xv.y, d2 = ev.z-xv.z, d3 = ev.w-xv.w;
    lsum += d0*d0 + d1*d1 + d2*d2 + d3*d3;
  }
  #pragma unroll
  for (int off = 1; off < 64; off <<= 1) lsum += __shfl_xor(lsum, off);
  if (lane == 0) ls[wid] = lsum;
  __syncthreads();
  if (tid == 0)
    atomicAdd(out + (size_t)NELEM, (ls[0]+ls[1]+ls[2]+ls[3]) * (1.25f/8388608.0f));
}

// ================================ launch ======================================
extern "C" void kernel_launch(void* const* d_in, const int* in_sizes, int n_in,
                              void* d_out, int out_size, void* d_ws, size_t ws_size,
                              hipStream_t stream)
{
  const float* X = (const float*)d_in[0];   // [32768][256]
  const float* E = (const float*)d_in[1];   // [256][8192]
  float* out = (float*)d_out;               // [8388608 quantized][1 loss]
  char* ws = (char*)d_ws;

  float*     Et        = (float*)(ws);                               // 8 MB
  _Float16*  EhP       = (_Float16*)(ws + 8388608);                  // 4 MB
  float*     e2n       = (float*)(ws + 12582912);                    // 32 KB
  unsigned*  m1q       = (unsigned*)(ws + 12615680);                 // 512 KB
  unsigned*  m2q       = (unsigned*)(ws + 13139968);                 // 512 KB
  float*     m1s       = (float*)(ws + 13664256);                    // 128 KB
  int*       idx       = (int*)(ws + 13795328);                      // 128 KB
  int*       flaglist  = (int*)(ws + 13926400);                      // 64 KB
  int*       ccounts   = (int*)(ws + 13991936);                      // 64 KB
  int*       candbuf   = (int*)(ws + 14057472);                      // 1 MB
  int*       flagcount = (int*)(ws + 15106048);                      // 4 B
  if (ws_size < (size_t)15106052) return;

  dim3 B(256);
  k_prepE <<<dim3(512),  B, 0, stream>>>(E, EhP, Et);
  k_e2z   <<<dim3(2048), B, 0, stream>>>(Et, e2n, ccounts, flagcount, out + NELEM);
  k_screen<<<dim3(512),  B, 0, stream>>>(X, EhP, e2n, m1q, m2q);
  k_merge <<<dim3(128),  B, 0, stream>>>(m1q, m2q, idx, m1s, flaglist, flagcount);
  k_rescan<<<dim3(512),  B, 0, stream>>>(X, EhP, e2n, m1s, flaglist, flagcount, ccounts, candbuf);
  k_exact <<<dim3(256),  B, 0, stream>>>(X, Et, flaglist, flagcount, ccounts, candbuf, idx);
  k_gather<<<dim3(512),  B, 0, stream>>>(X, Et, idx, out);
}